// Round 8
// baseline (2031.327 us; speedup 1.0000x reference)
//
#include <hip/hip_runtime.h>
#include <stdint.h>

typedef uint32_t u32;
typedef uint16_t u16;
typedef __attribute__((ext_vector_type(8))) short bf16x8;
typedef __attribute__((ext_vector_type(4))) float f32x4;

__device__ __forceinline__ u16 f2bf(float f) {
  u32 u = __builtin_bit_cast(u32, f);
  return (u16)((u + 0x7FFFu + ((u >> 16) & 1u)) >> 16);
}
__device__ __forceinline__ u32 pack2bf(float a, float b) {
  return (u32)f2bf(a) | ((u32)f2bf(b) << 16);
}
__device__ __forceinline__ uint4 pack8bf(float4 a, float4 b) {
  uint4 r;
  r.x = pack2bf(a.x, a.y); r.y = pack2bf(a.z, a.w);
  r.z = pack2bf(b.x, b.y); r.w = pack2bf(b.z, b.w);
  return r;
}
__device__ __forceinline__ float sigmoid_(float x) { return 1.0f / (1.0f + __expf(-x)); }
__device__ __forceinline__ float tanh_(float x) { return 1.0f - 2.0f / (1.0f + __expf(2.0f * x)); }

// ---------------------------------------------------------------------------
// Persistent LSTM.
// [R8] post-mortem R7: FAILED (absmax 3.7e-2) — protocol bug, not structure.
//  I moved to ONE accumulating counter per bgr but left the poll threshold
//  at the constant 16: after step 1 the counter is >=16 forever, so the
//  poll never blocks from t=3 on -> consumers raced ahead, stale h reads.
//  FIX: poll `< 16*(t-1)`. Counter after all 16 producers publish step s is
//  exactly 16s (lockstep: advancing to step s+1 requires >=16s, i.e. all
//  published). Partial sums 16(t-1)+k can't falsely satisfy 16*(t-1)... they
//  exceed it only legitimately. Parity hazard safe: writing h(t+1) (parity
//  of t-1) needs counter >= 16t, which includes THIS consumer's step-t
//  publish, which follows its staging read of h(t-1).
// [R7 structure, retained — TLP experiment now actually testable]:
//  two 8-batch WGs per R3-WG; grid 512 = 32 bgr x 16 ug, 256 thr,
//  launch_bounds(256,2) -> 2 WGs/CU = 8 waves/CU. Fan-in per chain: 16
//  producers (unchanged vs R3); stage 8KB/WG; lanes n>=8 duplicate row n&7
//  (LDS broadcast); only n<8 publish. h_buf bytes IDENTICAL to R3 ->
//  absmax must be exactly 0.0078125.
// ---------------------------------------------------------------------------
__global__ __launch_bounds__(256, 2) void lstm_kernel(
    const int* __restrict__ trg, const float* __restrict__ w_ih,
    const float* __restrict__ w_hh, const float* __restrict__ b_ih,
    const float* __restrict__ b_hh, u16* __restrict__ h_buf,
    int* __restrict__ flags) {
  __shared__ u16 Bb[8 * 520];      // h(t-1): [m 8][k 512+8 pad] bf16
  __shared__ float Xl[8 * 513];    // x inputs: [m 8][t 512+1 pad] f32
  __shared__ u32 Hs[128];          // h(t) gather: [m 8][u32pos 16]
  const int tid = threadIdx.x;
  const int wave = tid >> 6, lane = tid & 63;
  const int q = lane >> 4, n = lane & 15;
  const int m = n & 7;  // local batch 0..7 (lanes n>=8 duplicate lane n-8)
  // perf-only bijective swizzle: decouple co-resident pairs (idx, idx+256)
  const int j = blockIdx.x ^ ((blockIdx.x >> 8) & 1);
  const int bgr = j & 31, ug = j >> 5;  // bgr 0..31 (8 batches), ug 0..15

  // ---- preload x = (float)trg for this bgr's 8 batches ----
  #pragma unroll
  for (int c = 0; c < 2; ++c) {
    int e = c * 2048 + tid * 8;
    int rn = e >> 9, t0 = e & 511;
    const int* src = trg + (bgr * 8 + rn) * 512 + t0;
    int4 a = *(const int4*)src;
    int4 b = *(const int4*)(src + 4);
    float* dst = &Xl[rn * 513 + t0];
    dst[0] = (float)a.x; dst[1] = (float)a.y; dst[2] = (float)a.z; dst[3] = (float)a.w;
    dst[4] = (float)b.x; dst[5] = (float)b.y; dst[6] = (float)b.z; dst[7] = (float)b.w;
  }

  // ---- preload w_hh slice: tile-interleaved rows, NATURAL k packing ----
  // A-row rit of tile i -> gate rit&3, unit ug*32 + wave*8 + 2*(rit>>2) + i
  bf16x8 Areg[2][16];
  const int rit = lane & 15;
  #pragma unroll
  for (int i = 0; i < 2; ++i) {
    int grow = (rit & 3) * 512 + ug * 32 + wave * 8 + 2 * (rit >> 2) + i;
    const float* wr = w_hh + (size_t)grow * 512;
    #pragma unroll
    for (int ks = 0; ks < 16; ++ks) {
      const float* p = wr + ks * 32 + q * 8;
      float4 f0 = *(const float4*)p;
      float4 f1 = *(const float4*)(p + 4);
      Areg[i][ks] = __builtin_bit_cast(bf16x8, pack8bf(f0, f1));
    }
  }

  // per-lane input weights & bias: lane q, tile i -> unit ug*32 + wave*8 + 2q+i
  float wi[2][4], bs[2][4];
  #pragma unroll
  for (int i = 0; i < 2; ++i) {
    #pragma unroll
    for (int r = 0; r < 4; ++r) {
      int grow = r * 512 + ug * 32 + wave * 8 + q * 2 + i;
      wi[i][r] = w_ih[grow];
      bs[i][r] = b_ih[grow] + b_hh[grow];
    }
  }
  float cst[2] = {0.f, 0.f};  // cell: units ug*32+wave*8+2q+{0,1}, batch bgr*8+m
  __syncthreads();

  for (int t = 1; t <= 511; ++t) {
    // ---- wait for h(t-1): all lanes poll the per-bgr ACCUMULATING counter
    //      (one line, wave-coalesced broadcast). Threshold 16*(t-1). ----
    if (t > 1) {
      const int need = (t - 1) << 4;
      int cnt = 0;
      while (__hip_atomic_load(&flags[bgr * 128], __ATOMIC_RELAXED,
                               __HIP_MEMORY_SCOPE_AGENT) < need) {
        if (++cnt > (1 << 22)) break;  // convert deadlock into wrong answer
      }
    }
    // ---- stage B = h(t-1)[512 x 8] for this bgr (8KB, contiguous) ----
    {
      const u16* src = h_buf + (size_t)(((t - 1) & 1) * 16 + (bgr >> 1)) * 8192 +
                       (bgr & 1) * 4096;
      const u16* p0 = src + tid * 8;
      const u16* p1 = src + 2048 + tid * 8;
      uint4 d0, d1;
      asm volatile(
          "global_load_dwordx4 %0, %2, off sc0 sc1\n\t"
          "global_load_dwordx4 %1, %3, off sc0 sc1\n\t"
          "s_waitcnt vmcnt(0)"
          : "=&v"(d0), "=&v"(d1)
          : "v"(p0), "v"(p1)
          : "memory");
      #pragma unroll
      for (int c = 0; c < 2; ++c) {
        int e = c * 2048 + tid * 8;
        int rn = e >> 9, k = e & 511;
        uint4 d = (c == 0) ? d0 : d1;
        *(uint4*)&Bb[rn * 520 + k] = d;
      }
    }
    __syncthreads();

    f32x4 acc[2] = {{0.f, 0.f, 0.f, 0.f}, {0.f, 0.f, 0.f, 0.f}};
    const u16* brow = &Bb[m * 520];  // lanes n and n+8: same row (broadcast)
    #pragma unroll
    for (int ks = 0; ks < 16; ++ks) {
      bf16x8 bf = *(const bf16x8*)(brow + ks * 32 + q * 8);
      acc[0] = __builtin_amdgcn_mfma_f32_16x16x32_bf16(Areg[0][ks], bf, acc[0], 0, 0, 0);
      acc[1] = __builtin_amdgcn_mfma_f32_16x16x32_bf16(Areg[1][ks], bf, acc[1], 0, 0, 0);
    }

    float x = Xl[m * 513 + (t - 1)];
    float hv0, hv1;
    #pragma unroll
    for (int i = 0; i < 2; ++i) {
      float pi = acc[i][0] + x * wi[i][0] + bs[i][0];
      float pf = acc[i][1] + x * wi[i][1] + bs[i][1];
      float pg = acc[i][2] + x * wi[i][2] + bs[i][2];
      float po = acc[i][3] + x * wi[i][3] + bs[i][3];
      float ig = sigmoid_(pi), fg = sigmoid_(pf), og = sigmoid_(po);
      float gg = tanh_(pg);
      cst[i] = fg * cst[i] + ig * gg;
      float h = og * tanh_(cst[i]);
      if (i == 0) hv0 = h; else hv1 = h;
    }

    // ---- gather h(t) in LDS (only n<8 lanes publish; n>=8 duplicates) ----
    if (n < 8) Hs[m * 16 + wave * 4 + q] = pack2bf(hv0, hv1);
    __syncthreads();
    if (tid < 128) {
      u32 hv = Hs[tid];
      // u32 index: parity*65536 + (bg16*16 + n16)*256 + ug*16 + pos
      // bg16 = bgr>>1, n16 = (bgr&1)*8 + (tid>>4)  -> bytes identical to R3
      u32* dst = (u32*)h_buf + (size_t)((t & 1) ? 65536 : 0) +
                 (size_t)((bgr >> 1) * 16 + (bgr & 1) * 8 + (tid >> 4)) * 256 +
                 ug * 16 + (tid & 15);
      asm volatile("global_store_dword %0, %1, off sc1\n\ts_waitcnt vmcnt(0)"
                   :: "v"(dst), "v"(hv) : "memory");
    }
    __syncthreads();  // all stores drained before the flag add
    if (tid == 0) {
      __hip_atomic_fetch_add(&flags[bgr * 128], 1, __ATOMIC_RELAXED,
                             __HIP_MEMORY_SCOPE_AGENT);
    }
  }
}

// ---------------------------------------------------------------------------
// Head GEMM (R2's proven version): out[b][m] = sum_k A[m][k]*B[b][k] (+bias),
// A fp32 MxK, B bf16 [256][K]. M=128/WG, N=256. mode 0: relu+bf16 out (fc1),
// mode 1: fp32 out (fc2). Out leading dim == M for both uses.
// ---------------------------------------------------------------------------
__global__ __launch_bounds__(256, 1) void head_gemm(
    const float* __restrict__ A, const u16* __restrict__ B,
    const float* __restrict__ bias, void* __restrict__ outv,
    int M, int K, int mode) {
  __shared__ u16 Ach[128 * 40];
  __shared__ u16 Bch[256 * 40];
  const int tid = threadIdx.x;
  const int wave = tid >> 6, lane = tid & 63;
  const int q = lane >> 4, l15 = lane & 15;
  const int mblk = blockIdx.x * 128;
  const int nch = K >> 5;
  f32x4 acc[2][16];
  #pragma unroll
  for (int i = 0; i < 2; ++i)
    #pragma unroll
    for (int nb = 0; nb < 16; ++nb) acc[i][nb] = (f32x4){0.f, 0.f, 0.f, 0.f};

  for (int ch = 0; ch < nch; ++ch) {
    __syncthreads();
    {  // A chunk: 128 rows x 32 k, fp32 -> bf16
      int row = tid >> 1, k = (tid & 1) * 16;
      const float* src = A + (size_t)(mblk + row) * K + ch * 32 + k;
      float4 f0 = *(const float4*)src;
      float4 f1 = *(const float4*)(src + 4);
      float4 f2 = *(const float4*)(src + 8);
      float4 f3 = *(const float4*)(src + 12);
      u16* dst = &Ach[row * 40 + k];
      *(uint4*)dst = pack8bf(f0, f1);
      *(uint4*)(dst + 8) = pack8bf(f2, f3);
    }
    #pragma unroll
    for (int c = 0; c < 4; ++c) {  // B chunk: 256 rows x 32 k bf16
      int e = c * 2048 + tid * 8;
      int nr = e >> 5, k = e & 31;
      uint4 d = *(const uint4*)(B + (size_t)nr * K + ch * 32 + k);
      *(uint4*)&Bch[nr * 40 + k] = d;
    }
    __syncthreads();
    bf16x8 a0 = *(const bf16x8*)&Ach[((wave * 2 + 0) * 16 + l15) * 40 + q * 8];
    bf16x8 a1 = *(const bf16x8*)&Ach[((wave * 2 + 1) * 16 + l15) * 40 + q * 8];
    #pragma unroll
    for (int nb = 0; nb < 16; ++nb) {
      bf16x8 bf = *(const bf16x8*)&Bch[(nb * 16 + l15) * 40 + q * 8];
      acc[0][nb] = __builtin_amdgcn_mfma_f32_16x16x32_bf16(a0, bf, acc[0][nb], 0, 0, 0);
      acc[1][nb] = __builtin_amdgcn_mfma_f32_16x16x32_bf16(a1, bf, acc[1][nb], 0, 0, 0);
    }
  }
  #pragma unroll
  for (int i = 0; i < 2; ++i) {
    int j0 = mblk + (wave * 2 + i) * 16 + q * 4;
    float4 bv = *(const float4*)(bias + j0);
    #pragma unroll
    for (int nb = 0; nb < 16; ++nb) {
      int b = nb * 16 + l15;
      f32x4 v = acc[i][nb];
      v[0] += bv.x; v[1] += bv.y; v[2] += bv.z; v[3] += bv.w;
      if (mode == 0) {
        v[0] = fmaxf(v[0], 0.f); v[1] = fmaxf(v[1], 0.f);
        v[2] = fmaxf(v[2], 0.f); v[3] = fmaxf(v[3], 0.f);
        u16* z = (u16*)outv;
        uint2 pk;
        pk.x = pack2bf(v[0], v[1]);
        pk.y = pack2bf(v[2], v[3]);
        *(uint2*)(z + (size_t)b * M + j0) = pk;
      } else {
        float* op = (float*)outv + (size_t)b * M + j0;
        float4 o;
        o.x = v[0]; o.y = v[1]; o.z = v[2]; o.w = v[3];
        *(float4*)op = o;
      }
    }
  }
}

// ---------------------------------------------------------------------------
// Workspace layout (bytes):
//   [0,        524288)  h_buf: [parity 2][bg 16][n 16][k 512] bf16, natural
//   [524288,   540672)  flags: [bgr 32] int at 512B stride, ACCUMULATING
//                       (16 adds/step; value after step s == 16*s)
//   [557056,  1081344)  z: [256][1024] bf16
// ---------------------------------------------------------------------------
extern "C" void kernel_launch(void* const* d_in, const int* in_sizes, int n_in,
                              void* d_out, int out_size, void* d_ws, size_t ws_size,
                              hipStream_t stream) {
  (void)in_sizes; (void)n_in; (void)out_size; (void)ws_size;
  const int* trg = (const int*)d_in[2];
  const float* w_ih = (const float*)d_in[3];
  const float* w_hh = (const float*)d_in[4];
  const float* b_ih = (const float*)d_in[5];
  const float* b_hh = (const float*)d_in[6];
  const float* fc1_w = (const float*)d_in[7];
  const float* fc1_b = (const float*)d_in[8];
  const float* fc2_w = (const float*)d_in[9];
  const float* fc2_b = (const float*)d_in[10];

  u16* h_buf = (u16*)d_ws;
  int* flags = (int*)((char*)d_ws + 524288);
  u16* z = (u16*)((char*)d_ws + 557056);

  hipMemsetAsync(d_ws, 0, 262144, stream);                  // h parity 0 = h(0) = 0
  hipMemsetAsync((char*)d_ws + 524288, 0, 32768, stream);   // flags = 0

  lstm_kernel<<<512, 256, 0, stream>>>(trg, w_ih, w_hh, b_ih, b_hh, h_buf, flags);

  const u16* h_final = h_buf + 131072;  // parity 1 == h(511), layout [b][512]
  head_gemm<<<8, 256, 0, stream>>>(fc1_w, h_final, fc1_b, (void*)z, 1024, 512, 0);
  head_gemm<<<250, 256, 0, stream>>>(fc2_w, z, fc2_b, d_out, 32000, 1024, 1);
}